// Round 3
// baseline (59.102 us; speedup 1.0000x reference)
//
#include <hip/hip_runtime.h>

#define NPTS   8192
#define BATCH  2
#define CH     64

#define IPT    4              // i's per thread
#define ITILE  (IPT*256)      // 1024 i's per block
#define JTILE  64             // j's per block (staged in LDS)
#define NIT    (NPTS/ITILE)   // 8
#define NJT    (NPTS/JTILE)   // 128
#define RATIO  (ITILE/JTILE)  // 16
#define NBLK   (BATCH*NIT*NJT) // 2048

// ---------------- Kernel 1: Fsim = W @ l0 + b (SoA), + counter reset ----------------
__global__ __launch_bounds__(256) void fsim_kernel(
    const float* __restrict__ l0,    // [B, C, N]
    const float* __restrict__ W,     // [3, C]
    const float* __restrict__ bias,  // [3]
    float* __restrict__ fx, float* __restrict__ fy, float* __restrict__ fz,
    int* __restrict__ counter)
{
    if (blockIdx.x == 0 && threadIdx.x == 0)
        __hip_atomic_store(counter, 0, __ATOMIC_RELAXED, __HIP_MEMORY_SCOPE_AGENT);

    __shared__ float sW[3 * CH];
    const int tid = threadIdx.x;
    if (tid < 3 * CH) sW[tid] = W[tid];
    __syncthreads();

    const int lane = tid & 63;
    const int wave = tid >> 6;
    const int p    = lane & 15;          // point within wave
    const int cg   = lane >> 4;          // channel group (0..3), 16 ch each
    const int pt   = blockIdx.x * 64 + wave * 16 + p;
    const int b    = pt >> 13;
    const int n    = pt & (NPTS - 1);

    const float* base = l0 + (size_t)b * CH * NPTS + n;
    float ax = 0.f, ay = 0.f, az = 0.f;
    #pragma unroll
    for (int k = 0; k < 16; ++k) {
        int c = cg * 16 + k;
        float v = base[(size_t)c * NPTS];
        ax = fmaf(sW[c],        v, ax);
        ay = fmaf(sW[CH + c],   v, ay);
        az = fmaf(sW[2*CH + c], v, az);
    }
    ax += __shfl_down(ax, 32, 64); ay += __shfl_down(ay, 32, 64); az += __shfl_down(az, 32, 64);
    ax += __shfl_down(ax, 16, 64); ay += __shfl_down(ay, 16, 64); az += __shfl_down(az, 16, 64);
    if (cg == 0) {
        fx[pt] = ax + bias[0];
        fy[pt] = ay + bias[1];
        fz[pt] = az + bias[2];
    }
}

// ---------------- Kernel 2: upper-triangle pairwise loss + last-block reduce ----------------
__global__ __launch_bounds__(256) void pair_kernel(
    const float* __restrict__ fx, const float* __restrict__ fy,
    const float* __restrict__ fz, const int* __restrict__ target,
    double* __restrict__ partials, int* __restrict__ counter,
    float* __restrict__ out)
{
    const int jt  = blockIdx.x;   // 0..127
    const int it  = blockIdx.y;   // 0..7
    const int b   = blockIdx.z;   // 0..1
    const int tid = threadIdx.x;
    const int bid = (b * NIT + it) * NJT + jt;
    const int base = b * NPTS;

    __shared__ float4 sj[JTILE];
    __shared__ double wsum[4];
    __shared__ int elect;

    double blockSum = 0.0;
    const bool below = (jt < it * RATIO);           // tile fully below diagonal: no work
    if (!below) {
        const bool crossing = (jt < (it + 1) * RATIO);

        float ix[IPT], iy[IPT], iz[IPT];
        int   il[IPT], ii[IPT];
        #pragma unroll
        for (int u = 0; u < IPT; ++u) {
            int i = it * ITILE + u * 256 + tid;
            ii[u] = i;
            ix[u] = fx[base + i]; iy[u] = fy[base + i]; iz[u] = fz[base + i];
            int l = target[base + i];
            il[u] = (l == -1) ? 0x7fffffff : l;     // sentinel: never matches any lj
        }
        if (tid < JTILE) {
            int k = jt * JTILE + tid;
            sj[tid] = make_float4(fx[base + k], fy[base + k], fz[base + k],
                                  __int_as_float(target[base + k]));
        }
        __syncthreads();

        float acc[IPT] = {0.f, 0.f, 0.f, 0.f};
        if (!crossing) {
            // fully above diagonal: every pair counts
            #pragma unroll 4
            for (int j = 0; j < JTILE; ++j) {
                float4 q = sj[j];
                int lj = __float_as_int(q.w);
                #pragma unroll
                for (int u = 0; u < IPT; ++u) {
                    float dx = ix[u] - q.x, dy = iy[u] - q.y, dz = iz[u] - q.z;
                    float d  = fmaf(dx, dx, fmaf(dy, dy, dz * dz));
                    float t  = d + 1.0f;
                    float r  = __builtin_amdgcn_rcpf(t);
                    float e  = 2.0f * (r * r);
                    acc[u] += (il[u] == lj) ? d : e;
                }
            }
        } else {
            // diagonal-crossing tile: count only i < j
            #pragma unroll 4
            for (int j = 0; j < JTILE; ++j) {
                float4 q = sj[j];
                int lj = __float_as_int(q.w);
                int jg = jt * JTILE + j;
                #pragma unroll
                for (int u = 0; u < IPT; ++u) {
                    float dx = ix[u] - q.x, dy = iy[u] - q.y, dz = iz[u] - q.z;
                    float d  = fmaf(dx, dx, fmaf(dy, dy, dz * dz));
                    float t  = d + 1.0f;
                    float r  = __builtin_amdgcn_rcpf(t);
                    float e  = 2.0f * (r * r);
                    float term = (il[u] == lj) ? d : e;
                    acc[u] += (ii[u] < jg) ? term : 0.0f;
                }
            }
        }
        float accs = (acc[0] + acc[1]) + (acc[2] + acc[3]);
        #pragma unroll
        for (int off = 32; off > 0; off >>= 1)
            accs += __shfl_down(accs, off, 64);
        if ((tid & 63) == 0) wsum[tid >> 6] = (double)accs;
        __syncthreads();
        if (tid == 0) blockSum = wsum[0] + wsum[1] + wsum[2] + wsum[3];
    }

    // ---- tail: every block participates in the election ----
    if (tid == 0) {
        partials[bid] = blockSum;
        __threadfence();                        // release partials (agent scope)
        int old = atomicAdd(counter, 1);        // device-scope by default
        elect = (old == NBLK - 1) ? 1 : 0;
    }
    __syncthreads();
    if (!elect) return;
    __threadfence();                            // acquire all partials

    // elected (last) block: deterministic final reduction
    double s = 0.0;
    for (int k = tid; k < NBLK; k += 256) {
        unsigned long long uv = __hip_atomic_load(
            (unsigned long long*)&partials[k], __ATOMIC_RELAXED, __HIP_MEMORY_SCOPE_AGENT);
        s += __longlong_as_double(uv);
    }
    #pragma unroll
    for (int off = 32; off > 0; off >>= 1)
        s += __shfl_down(s, off, 64);
    __shared__ double sd[4];
    if ((tid & 63) == 0) sd[tid >> 6] = s;
    __syncthreads();
    if (tid == 0) {
        double tot = sd[0] + sd[1] + sd[2] + sd[3];
        // sum over all ordered pairs = 2 * triangle sum; diagonal contributes 0
        out[0] = (float)(200.0 * tot / ((double)BATCH * NPTS * NPTS));
    }
}

extern "C" void kernel_launch(void* const* d_in, const int* in_sizes, int n_in,
                              void* d_out, int out_size, void* d_ws, size_t ws_size,
                              hipStream_t stream) {
    const float* l0     = (const float*)d_in[0];   // [2,64,8192]
    const float* W      = (const float*)d_in[1];   // [3,64]
    const float* bias   = (const float*)d_in[2];   // [3]
    const int*   target = (const int*)d_in[3];     // [2,8192]
    float* out = (float*)d_out;

    float* fx = (float*)d_ws;
    float* fy = fx + BATCH * NPTS;
    float* fz = fy + BATCH * NPTS;
    double* partials = (double*)((char*)d_ws + 3 * BATCH * NPTS * sizeof(float) + 256);
    int* counter = (int*)((char*)partials + NBLK * sizeof(double));

    fsim_kernel<<<BATCH * NPTS / 64, 256, 0, stream>>>(l0, W, bias, fx, fy, fz, counter);

    dim3 grid(NJT, NIT, BATCH);   // (128, 8, 2) = 2048 blocks, 896 exit instantly
    pair_kernel<<<grid, 256, 0, stream>>>(fx, fy, fz, target, partials, counter, out);
}